// Round 13
// baseline (284.500 us; speedup 1.0000x reference)
//
#include <hip/hip_runtime.h>

// ---------------------------------------------------------------------------
// STFT-Fourier-KAN DGCNN on MI355X.
// R31 (284.9): detect deleted, knn+tkan merged. R32 (278.3, best): kan<1>
// fused INTO kan<2> (embedded L1 phase computes the wave's 80 slab rows
// in-place; h1 21MB roundtrip + launch + boundary deleted; FETCH 10.5->3.6MB
// confirms). kan<2>~76 / kan<3>~75 plateaus structural. Boundary model
// (~10us/launch) validated 3x (R30 l4-split, R31 merge, R32 fuse).
// R33: fuse outred INTO l4 (last-block-reduce). Each of l4's 240 blocks
// does __threadfence()+atomicAdd(cnt) after writing its part slice; the
// block seeing 239 runs outred in-block (320 outputs, 256 threads, 2/thread
// for t<64; identical reduce order -> same absmax). cnt zeroed by prep
// (stream-ordered before l4). Device-scope atomics+fences per G12/G16.
// Everything else byte-identical to R32.
// ---------------------------------------------------------------------------

typedef unsigned short u16;
typedef unsigned int   u32;
typedef unsigned long long u64;
typedef __attribute__((ext_vector_type(8))) _Float16 half8;
typedef __attribute__((ext_vector_type(4))) float f32x4;

__device__ __forceinline__ float bf2f(u16 u) {
  u32 v = ((u32)u) << 16;
  return __uint_as_float(v);
}
__device__ __forceinline__ u16 f2bfr(float f) {  // bf16 round-to-nearest-even
  u32 x = __float_as_uint(f);
  u32 r = x + 0x7FFFu + ((x >> 16) & 1u);
  return (u16)(r >> 16);
}
__device__ __forceinline__ u16 f2h(float f) {    // fp16 RTN bits
  _Float16 h = (_Float16)f;
  u16 r;
  __builtin_memcpy(&r, &h, 2);
  return r;
}
__device__ __forceinline__ float h2f(u16 u) {
  _Float16 h;
  __builtin_memcpy(&h, &u, 2);
  return (float)h;
}
// dtype-dispatched external load (flag wave-uniform -> scalar branch)
__device__ __forceinline__ float ldf(const void* p, size_t i, bool f32) {
  return f32 ? ((const float*)p)[i] : bf2f(((const u16*)p)[i]);
}
__device__ __forceinline__ u64 minu64(u64 a, u64 b) { return a < b ? a : b; }

// per-wave dtype detect: every wave reads pos[0..63] as f32 and ballots the
// "plausible float" test -- wave-uniform result, no global flag roundtrip.
__device__ __forceinline__ bool wave_detect(const void* pos) {
  float a = fabsf(((const float*)pos)[threadIdx.x & 63]);
  bool ok = (a > 1.0e-3f && a < 100.0f);
  unsigned long long m = __ballot(ok);
  return __popcll(m) >= 32;
}

// ---------------- workspace layout (bytes) ----------------
#define NBR_OFF   ((size_t)0)                       // int32 [163840]       655,360
#define CNT_OFF   ((size_t)917504)                  // int32 [1] l4 block counter
#define L4P_OFF   (((size_t)(1u << 20)) + 131072)   // f32 [8][15][240]     115,200
#define C1T_OFF   (((size_t)(1u << 20)) + 524288)   // fp16 [64][64]          8,192
#define C2T_OFF   (((size_t)(1u << 20)) + 589824)   // fp16 [128][1120]     286,720
#define C3T_OFF   ((size_t)(2u << 20))              // fp16 [1024][2240]  4,587,520
#define C4T_OFF   ((size_t)(7u << 20))              // f32  [40][38400]   6,144,000
#define PMAX_OFF  ((size_t)(13u << 20))             // f32 [256][1024]    1,048,576
#define PSUM_OFF  ((size_t)(14u << 20))             // f32 [256][1024]    1,048,576
#define X1_OFF    ((size_t)(15u << 20))             // fp16 [8192][128]   2,097,152
// peak ~17 MB

// ---------------- tkan transpose body (compile-time constants) --------------
// Angle-major k-order: p < 4*NA: aa=p>>2, g=(p&3)+1 ; p in [4*NA,5*NA):
// aa=p-4*NA, g=5. f = 2*p + part. Pad f>=Kt with zeros.
template <int DOUT, int NW, int WW, int KPAD, int OUTF32>
__device__ __forceinline__ void tkan_body(const void* __restrict__ src,
                                          void* __restrict__ dst,
                                          int id, bool f32) {
  constexpr int NA = NW * WW;
  constexpr int Kt = NA * 10;
  constexpr int OS = NA * 5;
  const int o = id / KPAD, f = id % KPAD;   // literal KPAD -> magic multiply
  float v = 0.f;
  if (f < Kt) {
    const int part = f & 1, p = f >> 1;
    int aa, gg;
    if (p < 4 * NA) { aa = p >> 2;      gg = p & 3; }
    else            { aa = p - 4 * NA;  gg = 4;     }
    const int i = aa % WW, w = aa / WW;     // literal WW
    size_t sidx = (size_t)part * (DOUT * OS) + (size_t)o * OS +
                  (size_t)w * (WW * 5) + i * 5 + gg;
    v = ldf(src, sidx, f32);
  }
  if (OUTF32) ((float*)dst)[id] = v;
  else        ((u16*)dst)[id] = f2h(v);
}

// ---------------- merged prep: knn [0,2048) + coeff transpose [2048,17584) --
__global__ __launch_bounds__(256) void prep_kernel(
    const void* __restrict__ pos, int* __restrict__ nbr,
    const void* __restrict__ s1, void* __restrict__ d1,
    const void* __restrict__ s2, void* __restrict__ d2,
    const void* __restrict__ s3, void* __restrict__ d3,
    const void* __restrict__ s4, void* __restrict__ d4,
    int* __restrict__ cnt) {
  __shared__ float px[1024], py[1024], pz[1024];
  const bool f32 = wave_detect(pos);
  const int blk = blockIdx.x;
  const int t = threadIdx.x;
  if (blk == 0 && t == 0) *cnt = 0;          // reset l4's block counter

  if (blk >= 2048) {                         // ---- coeff transpose part ----
    const int tb = blk - 2048;
    if (tb < 16) {
      tkan_body<64, 2, 3, 64, 0>(s1, d1, tb * 256 + t, f32);
    } else if (tb < 576) {
      tkan_body<128, 7, 16, 1120, 0>(s2, d2, (tb - 16) * 256 + t, f32);
    } else if (tb < 9536) {
      tkan_body<1024, 7, 32, 2240, 0>(s3, d3, (tb - 576) * 256 + t, f32);
    } else {
      tkan_body<40, 15, 256, 38400, 1>(s4, d4, (tb - 9536) * 256 + t, f32);
    }
    return;
  }

  // ---- brute-force kNN: one wave per query ----
  const int b = blk >> 8;                    // cloud [0,8)
  const int x = blk & 255;                   // query group [0,256)
  const int base = b << 10;
  for (int j = t; j < 1024; j += 256) {
    size_t pidx = (size_t)(base + j) * 3;
    px[j] = ldf(pos, pidx, f32);
    py[j] = ldf(pos, pidx + 1, f32);
    pz[j] = ldf(pos, pidx + 2, f32);
  }
  __syncthreads();
  const int wv = t >> 6, lane = t & 63;
  const int q = x * 4 + wv;
  const float qx = px[q], qy = py[q], qz = pz[q];
  u64 key[16];
#pragma unroll
  for (int s = 0; s < 16; ++s) {
    const int j = s * 64 + lane;
    float dx = qx - px[j], dy = qy - py[j], dz = qz - pz[j];
    float d = __fadd_rn(__fadd_rn(__fmul_rn(dx, dx), __fmul_rn(dy, dy)),
                        __fmul_rn(dz, dz));
    key[s] = (j == q) ? ~0ull
                      : ((((u64)__float_as_uint(d)) << 32) | (u32)j);
  }
  const int obase = (base + q) * 20;
  for (int k = 0; k < 20; ++k) {
    u64 m = key[0];
#pragma unroll
    for (int s = 1; s < 16; ++s) m = minu64(m, key[s]);
#pragma unroll
    for (int off = 32; off >= 1; off >>= 1) {
      u32 lo = (u32)m, hi = (u32)(m >> 32);
      lo = __shfl_xor(lo, off, 64);
      hi = __shfl_xor(hi, off, 64);
      m = minu64(m, (((u64)hi) << 32) | lo);
    }
    if (lane == 0) nbr[obase + k] = (int)(u32)m;
#pragma unroll
    for (int s = 0; s < 16; ++s)
      if (key[s] == m) key[s] = ~0ull;  // idx embedded -> unique, safe
  }
}

// ---------------- MFMA KAN layer, LDS double-buffered B ---------------------
// L==2 additionally embeds the L1 layer: each wave computes its 80 slab rows
// of h1 in-place (acc1[5][4], NCH1=2, B direct from 8KB L1-resident c1t).
// Per chunk: 256 threads each load NPC 16B pieces of next chunk's B, build
// NEXT chunk's A fragments (pipelined one ahead), MFMA current chunk from
// Bbuf ds_read_b128 + last iter's af, then ds_write+barrier.
// PSTH=DIN+4 halves: lane stride -> 16 distinct banks.
template <int L>
__global__ __launch_bounds__(256, (L == 2) ? 2 : 3) void kan_kernel(
    const void* __restrict__ in_, const int* __restrict__ nbr,
    const void* __restrict__ pos, const u16* __restrict__ ct,
    const void* __restrict__ bias, void* __restrict__ out_,
    float* __restrict__ pmax, float* __restrict__ psum,
    const u16* __restrict__ ct1, const void* __restrict__ bias1) {
  constexpr int W    = (L == 2) ? 16  : 32;
  constexpr int S    = (L == 2) ? 8   : 16;
  constexpr int DIN  = (L == 2) ? 64  : 128;
  constexpr int NT   = (L == 2) ? 128 : 64;         // L2: full 128-col tile
  constexpr int NW   = (DIN - W) / S + 1;
  constexpr int NA   = NW * W;                      // angles
  constexpr int NPAIR = NA * 5;
  constexpr int S1P  = NA * 4;                      // section-1 pairs (g=1..4)
  constexpr int KROW  = NPAIR * 2;                  // ct row stride
  constexpr int NCH   = KROW / 32;                  // L2:35(odd!)  L3:70
  constexpr int NB    = NT / 16;                    // 8 or 4
  constexpr int RW    = (L == 2) ? 80 : 32;         // rows per wave
  constexpr int MB    = RW / 16;
  constexpr int PSTH  = DIN + 4;                    // slab stride (halves)
  constexpr int LGW   = (W == 16) ? 4 : 5;          // log2(W)
  constexpr int BCS   = NT * 8 + 8;                 // Bbuf halves per part
  constexpr int BBS   = 4 * BCS;                    // Bbuf halves per buffer
  constexpr int NPC   = NT / 64;                    // 16B B-pieces per thread

  __shared__ float hamS[W];
  __shared__ float wT1[(L == 2) ? 32 : 1];          // embedded-L1 tables
  __shared__ int   hT1[(L == 2) ? 32 : 1];
  __shared__ u16   slab[4 * RW * PSTH];
  __shared__ u16   Bbuf[2 * BBS];                   // [buf][part(4)][BCS]

  const bool f32 = wave_detect(pos);
  const u16* inH = (const u16*)in_;
  const int t = threadIdx.x;
  if (t < W) hamS[t] = 0.54f - 0.46f * cospif(2.0f * (float)t / (float)(W - 1));
  if constexpr (L == 2) {
    // embedded-L1 angle tables (W1=3, NPAIR1=30, S1P1=24)
    if (t < 32) {
      float wv_ = 0.f; int hx = 0;
      if (t < 30) {
        int aa, gg;
        if (t < 24) { aa = t >> 2;  gg = t & 3; }
        else        { aa = t - 24;  gg = 4;     }
        int i = aa % 3;
        float hm = 0.54f - 0.46f * cospif((float)i);   // 2*i/(3-1) = i
        wv_ = hm * (float)(gg + 1);
        hx = aa;
      }
      wT1[t] = wv_; hT1[t] = hx;
    }
  }

  // ---- block index: L3 uses XCD-aware swizzle (id%8-equal share 2 slices) --
  int tile, ncol0;
  if constexpr (L == 3) {
    const int id = blockIdx.x;                      // 1024 linear
    tile = (id >> 3) & 63;
    ncol0 = ((((id & 7) << 1) | (id >> 9))) * NT;
  } else {
    tile = blockIdx.x;
    ncol0 = 0;
  }
  const int lane = t & 63, wv = t >> 6;
  const int m16 = lane & 15, kb = lane >> 4;
  const int rowbase = tile * (4 * RW) + wv * RW;
  u16* myslab = &slab[wv * RW * PSTH];

  // B staging indices: piece p covers col=p>>2, part=p&3 (16B each)
  const u16* srcB[NPC];
  int sdst[NPC];
#pragma unroll
  for (int p_ = 0; p_ < NPC; ++p_) {
    const int pid = t + p_ * 256;
    const int scol = pid >> 2, spart = pid & 3;
    srcB[p_] = ct + (size_t)(ncol0 + scol) * KROW + spart * 8;
    sdst[p_] = spart * BCS + scol * 8;
  }

  // ---- stage wave-private fp16 slab from global input (L3 only) ----
  if constexpr (L == 3) {
    constexpr int F4R = DIN / 4;
    constexpr int TOT = RW * F4R;
    for (int i = lane; i < TOT; i += 64) {
      const int r = i / F4R, c4 = i % F4R;
      *(uint2*)(myslab + r * PSTH + c4 * 4) =
          *(const uint2*)(inH + (size_t)(rowbase + r) * DIN + c4 * 4);
    }
  }

  // ---- prologue: stage B chunk 0 ----
#pragma unroll
  for (int p_ = 0; p_ < NPC; ++p_) {
    const uint4 v = *(const uint4*)srcB[p_];
    *(uint4*)(Bbuf + sdst[p_]) = v;
  }
  __syncthreads();  // covers hamS/wT1/hT1 + Bbuf[0]

  // ---- embedded L1 phase (L==2): compute this wave's 80 slab rows of h1 ---
  if constexpr (L == 2) {
    f32x4 acc1[5][4];
#pragma unroll
    for (int mb = 0; mb < 5; ++mb)
#pragma unroll
      for (int nb = 0; nb < 4; ++nb) {
        acc1[mb][nb][0] = 0.f; acc1[mb][nb][1] = 0.f;
        acc1[mb][nb][2] = 0.f; acc1[mb][nb][3] = 0.f;
      }
#pragma unroll
    for (int c = 0; c < 2; ++c) {            // NCH1 = 2 (K padded 60->64)
      const int pg0 = c * 16 + kb * 4;
      float wm[4]; int hx[4]; bool val[4];
#pragma unroll
      for (int u = 0; u < 4; ++u) {
        const int pg = pg0 + u;
        wm[u] = wT1[pg]; hx[u] = hT1[pg]; val[u] = (pg < 30);
      }
      half8 af1[5];
#pragma unroll
      for (int mb = 0; mb < 5; ++mb) {
        const int row = rowbase + mb * 16 + m16;
        const int pt = row / 20;
        const int cloud = pt >> 10, ci = pt & 1023;
        const int cb = cloud << 10;
        const int jl = nbr[row];
#pragma unroll
        for (int u = 0; u < 4; ++u) {
          float cs = 0.f, sn = 0.f;
          if (val[u]) {
            const int aa = hx[u];
            float v;
            if (aa < 3) {
              v = ldf(pos, (size_t)(cb + ci) * 3 + aa, f32);
            } else {
              const int cc2 = aa - 3;
              v = ldf(pos, (size_t)(cb + jl) * 3 + cc2, f32) -
                  ldf(pos, (size_t)(cb + ci) * 3 + cc2, f32);
            }
            const float ang = v * wm[u];
            cs = __cosf(ang); sn = __sinf(ang);
          }
          af1[mb][2 * u]     = (_Float16)cs;
          af1[mb][2 * u + 1] = (_Float16)sn;
        }
      }
      // B direct from c1t [64 cols][64 k] -- 8KB, L1-cache-resident
#pragma unroll
      for (int nb = 0; nb < 4; ++nb) {
        const half8 bv = *(const half8*)(ct1 + (nb * 16 + m16) * 64 +
                                         c * 32 + kb * 8);
#pragma unroll
        for (int mb = 0; mb < 5; ++mb)
          acc1[mb][nb] = __builtin_amdgcn_mfma_f32_16x16x32_f16(
              af1[mb], bv, acc1[mb][nb], 0, 0, 0);
      }
    }
    // write h1 rows into wave-private slab (proven C-layout transform)
#pragma unroll
    for (int mb = 0; mb < 5; ++mb)
#pragma unroll
      for (int nb = 0; nb < 4; ++nb) {
        const float bsv = ldf(bias1, nb * 16 + m16, f32);
#pragma unroll
        for (int r = 0; r < 4; ++r)
          myslab[(mb * 16 + kb * 4 + r) * PSTH + nb * 16 + m16] =
              f2h(acc1[mb][nb][r] + bsv);
      }
    // same-wave LDS RAW below (compiler orders); no barrier needed
  }

  f32x4 acc[MB][NB];
#pragma unroll
  for (int mb = 0; mb < MB; ++mb)
#pragma unroll
    for (int nb = 0; nb < NB; ++nb) {
      acc[mb][nb][0] = 0.f; acc[mb][nb][1] = 0.f;
      acc[mb][nb][2] = 0.f; acc[mb][nb][3] = 0.f;
    }

  // ---- A-fragment builder for chunk c (reads slab only) ----
  auto build_af = [&](int c, half8* af) {
    const int pg0 = c * 16 + kb * 4;
    if (pg0 < S1P) {
      // section 1: one angle, g=1..4 -> Chebyshev recurrence
      const int aa = pg0 >> 2;
      const int i = aa & (W - 1), w = aa >> LGW;
      const int hidx = S * w + i;
      const float hm = hamS[i];
#pragma unroll
      for (int mb = 0; mb < MB; ++mb) {
        const u16* rp = myslab + (mb * 16 + m16) * PSTH;
        const float th = h2f(rp[hidx]) * hm;
        const float c1 = __cosf(th), s1 = __sinf(th);
        const float tc = 2.0f * c1;
        const float c2 = tc * c1 - 1.0f, s2 = tc * s1;
        const float c3 = tc * c2 - c1,   s3 = tc * s2 - s1;
        const float c4 = tc * c3 - c2,   s4 = tc * s3 - s2;
        af[mb][0] = (_Float16)c1; af[mb][1] = (_Float16)s1;
        af[mb][2] = (_Float16)c2; af[mb][3] = (_Float16)s2;
        af[mb][4] = (_Float16)c3; af[mb][5] = (_Float16)s3;
        af[mb][6] = (_Float16)c4; af[mb][7] = (_Float16)s4;
      }
    } else {
      // section 2: g=5 tail, 4 distinct angles, direct cos/sin
      const int q0 = pg0 - S1P;
      float wm[4]; int hx[4];
#pragma unroll
      for (int u = 0; u < 4; ++u) {
        const int aa = q0 + u;
        const int i = aa & (W - 1), w = aa >> LGW;
        hx[u] = S * w + i;
        wm[u] = hamS[i] * 5.0f;
      }
#pragma unroll
      for (int mb = 0; mb < MB; ++mb) {
        const u16* rp = myslab + (mb * 16 + m16) * PSTH;
#pragma unroll
        for (int u = 0; u < 4; ++u) {
          const float ang = h2f(rp[hx[u]]) * wm[u];
          af[mb][2 * u]     = (_Float16)__cosf(ang);
          af[mb][2 * u + 1] = (_Float16)__sinf(ang);
        }
      }
    }
  };

  // ---- one pipelined chunk: uses afc (built last iter), builds afn ----
  auto step = [&](int c, half8* afc, half8* afn) {
    const bool havenext = (c + 1 < NCH);
    // issue next chunk's B global load (overlaps everything below)
    uint4 bnext[NPC];
    if (havenext) {
#pragma unroll
      for (int p_ = 0; p_ < NPC; ++p_)
        bnext[p_] = *(const uint4*)(srcB[p_] + (c + 1) * 32);
    }
    // build NEXT chunk's A fragments; MFMA below consumes afc from LAST
    // iter -> trans chain off the MFMA critical path
    if (havenext) build_af(c + 1, afn);
    // MFMA: bv loaded per-nb (keep live set small -- R24 spill lesson)
    const u16* bb = Bbuf + (c & 1) * BBS + kb * BCS;
#pragma unroll
    for (int nb = 0; nb < NB; ++nb) {
      const half8 bv = *(const half8*)(bb + (nb * 16 + m16) * 8);
#pragma unroll
      for (int mb = 0; mb < MB; ++mb)
        acc[mb][nb] = __builtin_amdgcn_mfma_f32_16x16x32_f16(
            afc[mb], bv, acc[mb][nb], 0, 0, 0);
    }
    // commit next chunk's B to LDS, barrier
    if (havenext) {
#pragma unroll
      for (int p_ = 0; p_ < NPC; ++p_)
        *(uint4*)(Bbuf + ((c + 1) & 1) * BBS + sdst[p_]) = bnext[p_];
      __syncthreads();
    }
  };

  half8 afA[MB], afB[MB];
  build_af(0, afA);
  constexpr int NCH2 = (NCH / 2) * 2;  // even part: L2 34, L3 70
  for (int c = 0; c < NCH2; c += 2) {
    step(c, afA, afB);
    step(c + 1, afB, afA);
  }
  if constexpr ((NCH & 1) != 0) {
    // odd tail (L2: c=34). step(NCH2-1, afB, afA) built afA=af(NCH-1);
    // buf[(NCH-1)&1] was committed+barriered there. Consume it.
    step(NCH - 1, afA, afB);
  }

  // ---- fused epilogues (C layout: row=kb*4+r, col=m16 within 16x16) ----
  if constexpr (L == 2) {
    // C-tile (80x128) -> dead slab (stride PSTH) in two 64-col passes,
    // maxpool over 20 rows each pass, write x1 fp16
    u16* st = myslab;
    const int pbase = tile * 16 + wv * 4;       // 4 points per wave
#pragma unroll
    for (int h = 0; h < 2; ++h) {
#pragma unroll
      for (int mb = 0; mb < MB; ++mb)
#pragma unroll
        for (int nb4 = 0; nb4 < 4; ++nb4) {
          const int nb = h * 4 + nb4;
          const float bsv = ldf(bias, nb * 16 + m16, f32);
#pragma unroll
          for (int r = 0; r < 4; ++r)
            st[(mb * 16 + kb * 4 + r) * PSTH + nb4 * 16 + m16] =
                f2h(acc[mb][nb][r] + bsv);
        }
#pragma unroll
      for (int j = 0; j < 4; ++j) {
        float m = -3.0e38f;
#pragma unroll
        for (int k = 0; k < 20; ++k)
          m = fmaxf(m, h2f(st[(j * 20 + k) * PSTH + lane]));
        ((u16*)out_)[(size_t)(pbase + j) * 128 + h * 64 + lane] = f2h(m);
      }
    }
  } else {
    // in-register max/sum over 32 rows + kb butterfly -> pmax/psum partials
    const int chunk = rowbase >> 5;
#pragma unroll
    for (int nb = 0; nb < NB; ++nb) {
      const int col = ncol0 + nb * 16 + m16;
      const float bsv = ldf(bias, col, f32);
      float m = -3.0e38f, s = 0.f;
#pragma unroll
      for (int mb = 0; mb < MB; ++mb)
#pragma unroll
        for (int r = 0; r < 4; ++r) {
          const float v = acc[mb][nb][r] + bsv;
          m = fmaxf(m, v); s += v;
        }
#pragma unroll
      for (int off = 16; off <= 32; off <<= 1) {
        m = fmaxf(m, __shfl_xor(m, off, 64));
        s += __shfl_xor(s, off, 64);
      }
      if (kb == 0) {
        pmax[(size_t)chunk * 1024 + col] = m;
        psum[(size_t)chunk * 1024 + col] = s;
      }
    }
  }
}

// ---------------- layer 4 partials + fused final reduce ---------------------
// c4t GLOBAL layout (angle-major): window w section-1 (g1..4 quads) at
// o*38400 + w*2048 ; g5 tail at o*38400 + 30720 + w*512.
// grid (15,8,2): z splits the 6 dot slices into 2x3 (240 blocks).
// R33: last-finished block (atomicAdd counter) runs the former outred
// in-block: 320 outputs over 256 threads, identical reduce order.
__global__ __launch_bounds__(256) void l4_kernel(const float* __restrict__ pmax,
                                                 const float* __restrict__ psum,
                                                 const float* __restrict__ c4t,
                                                 float* __restrict__ part,
                                                 const void* __restrict__ b4,
                                                 const void* __restrict__ pos,
                                                 void* __restrict__ outp,
                                                 int* __restrict__ cnt) {
  __shared__ float F[2560];
  __shared__ int lastf;
  const int t = threadIdx.x;
  const bool f32 = wave_detect(pos);
  const int w = blockIdx.x, b = blockIdx.y, z = blockIdx.z;
  // fused segment combine (same reduce order as former seg2)
  const int ch = w * 128 + t;
  float xv;
  if (ch < 1024) {
    float m = -3.0e38f;
    for (int rc = 0; rc < 32; ++rc)
      m = fmaxf(m, pmax[(size_t)(b * 32 + rc) * 1024 + ch]);
    xv = m;
  } else {
    const int cc = ch - 1024;
    float s = 0.f;
    for (int rc = 0; rc < 32; ++rc)
      s += psum[(size_t)(b * 32 + rc) * 1024 + cc];
    xv = s * (1.0f / 1024.0f);
  }
  const float hm = 0.54f - 0.46f * cospif(2.0f * (float)t / 255.0f);
  const float aa = xv * hm;
  const float c1 = __cosf(aa), s1 = __sinf(aa);
  const float tc = 2.0f * c1;
  const float c2 = tc * c1 - 1.0f, s2 = tc * s1;
  const float c3 = tc * c2 - c1,   s3 = tc * s2 - s1;
  const float c4 = tc * c3 - c2,   s4 = tc * s3 - s2;
  const float a5 = aa * 5.0f;
  F[t * 8]     = c1; F[t * 8 + 1] = s1;
  F[t * 8 + 2] = c2; F[t * 8 + 3] = s2;
  F[t * 8 + 4] = c3; F[t * 8 + 5] = s3;
  F[t * 8 + 6] = c4; F[t * 8 + 7] = s4;
  F[2048 + t * 2]     = __cosf(a5);
  F[2048 + t * 2 + 1] = __sinf(a5);
  __syncthreads();
  if (t < 120) {
    const int o = t % 40, sl = t / 40;          // sl in [0,3)
    const int s = z * 3 + sl;                   // s in [0,6)
    const int f0 = s * 432;
    const int f1 = (f0 + 432 < 2560) ? (f0 + 432) : 2560;
    const float* cp1 = c4t + (size_t)o * 38400 + w * 2048;          // sec 1
    const float* cp2 = c4t + (size_t)o * 38400 + 30720 + w * 512;   // g5 tail
    float acc = 0.f;
    for (int f = f0; f < f1; f += 4) {   // 2048 boundary is float4-aligned
      const float* cpf = (f < 2048) ? (cp1 + f) : (cp2 + (f - 2048));
      const float4 cv = *(const float4*)cpf;
      const float4 fa = *(const float4*)&F[f];
      acc += fa.x * cv.x + fa.y * cv.y + fa.z * cv.z + fa.w * cv.w;
    }
    part[((b * 15 + w) * 6 + s) * 40 + o] = acc;
  }
  // ---- last-block final reduce (former outred_kernel) ----
  __syncthreads();                       // all part writes of this block done
  if (t == 0) {
    __threadfence();                     // release: part visible device-wide
    const int old = atomicAdd(cnt, 1);
    lastf = (old == 239) ? 1 : 0;
  }
  __syncthreads();
  if (lastf) {
    __threadfence();                     // acquire side
    for (int i = t; i < 320; i += 256) {
      const int bb = i / 40, o = i % 40;
      float s = ldf(b4, o, f32);
      for (int ww = 0; ww < 15; ++ww)
#pragma unroll
        for (int sl = 0; sl < 6; ++sl)
          s += part[((bb * 15 + ww) * 6 + sl) * 40 + o];
      if (f32) ((float*)outp)[i] = s;
      else     ((u16*)outp)[i] = f2bfr(s);
    }
  }
}

// ---------------------------------------------------------------------------
extern "C" void kernel_launch(void* const* d_in, const int* in_sizes, int n_in,
                              void* d_out, int out_size, void* d_ws,
                              size_t ws_size, hipStream_t stream) {
  (void)in_sizes; (void)n_in; (void)out_size; (void)ws_size;
  const void* pos = d_in[0];
  // d_in[1] = batch (int32) -- clouds are sorted equal-size, used implicitly
  const void* c1 = d_in[2];
  const void* b1 = d_in[3];
  const void* c2 = d_in[4];
  const void* b2 = d_in[5];
  const void* c3 = d_in[6];
  const void* b3 = d_in[7];
  const void* c4 = d_in[8];
  const void* b4 = d_in[9];

  char* ws = (char*)d_ws;
  int* nbr   = (int*)(ws + NBR_OFF);
  int* cnt   = (int*)(ws + CNT_OFF);
  float* l4p = (float*)(ws + L4P_OFF);
  u16* c1t   = (u16*)(ws + C1T_OFF);
  u16* c2t   = (u16*)(ws + C2T_OFF);
  u16* c3t   = (u16*)(ws + C3T_OFF);
  float* c4t = (float*)(ws + C4T_OFF);
  float* pmax = (float*)(ws + PMAX_OFF);
  float* psum = (float*)(ws + PSUM_OFF);
  u16* x1    = (u16*)(ws + X1_OFF);

  // merged prep: knn (blocks [0,2048)) + coeff transpose ([2048,17584))
  // + l4 counter reset (block 0)
  prep_kernel<<<17584, 256, 0, stream>>>(pos, nbr, c1, c1t, c2, c2t,
                                         c3, c3t, c4, c4t, cnt);

  // L1+L2 fused: 512 blocks x 320 rows; each wave computes its 80 h1 rows
  // in-slab (embedded L1) then runs the NT=128 L2 + maxpool
  kan_kernel<2><<<dim3(512), 256, 0, stream>>>(nullptr, nbr, pos, c2t,
                                               b2, x1, nullptr, nullptr,
                                               c1t, b1);
  // L3 fused segment partials: 1024 linear blocks, XCD-swizzled inside
  kan_kernel<3><<<1024, 256, 0, stream>>>(x1, nullptr, pos, c3t,
                                          b3, nullptr, pmax, psum,
                                          nullptr, nullptr);

  // l4 partials + fused last-block final reduce (former outred)
  l4_kernel<<<dim3(15, 8, 2), 256, 0, stream>>>(pmax, psum, c4t, l4p,
                                                b4, pos, d_out, cnt);
}

// Round 14
// 280.806 us; speedup vs baseline: 1.0132x; 1.0132x over previous
//
#include <hip/hip_runtime.h>

// ---------------------------------------------------------------------------
// STFT-Fourier-KAN DGCNN on MI355X.
// R32 (278.3us, BEST): kan<1> fused into kan<2> (embedded L1 phase; h1
// roundtrip + launch deleted), knn+tkan merged (R31), l4 z-split (R30).
// R33 post-mortem: outred-into-l4 last-block fusion REGRESSED 278.3->284.5.
// Revised boundary model: ~10us/boundary applies only between GPU-FILLING
// kernels (drain+ramp exposed); outred (1 block) launch was already
// pipelined under l4's tail -> nothing saved, while per-block threadfence/
// atomic/detect/extra-barrier across 240 blocks added ~6us.
// R34: exact revert to R32. kan<2>~76 / kan<3>~75 plateaus structural
// (5 levers each neutral/negative: VALU-halve, af-pipeline, barrier-free,
// NB=16 ratio, RW/occupancy). Remaining boundaries all separate
// GPU-filling kernels (minimal) or are proven-cheap (l4->outred).
// ---------------------------------------------------------------------------

typedef unsigned short u16;
typedef unsigned int   u32;
typedef unsigned long long u64;
typedef __attribute__((ext_vector_type(8))) _Float16 half8;
typedef __attribute__((ext_vector_type(4))) float f32x4;

__device__ __forceinline__ float bf2f(u16 u) {
  u32 v = ((u32)u) << 16;
  return __uint_as_float(v);
}
__device__ __forceinline__ u16 f2bfr(float f) {  // bf16 round-to-nearest-even
  u32 x = __float_as_uint(f);
  u32 r = x + 0x7FFFu + ((x >> 16) & 1u);
  return (u16)(r >> 16);
}
__device__ __forceinline__ u16 f2h(float f) {    // fp16 RTN bits
  _Float16 h = (_Float16)f;
  u16 r;
  __builtin_memcpy(&r, &h, 2);
  return r;
}
__device__ __forceinline__ float h2f(u16 u) {
  _Float16 h;
  __builtin_memcpy(&h, &u, 2);
  return (float)h;
}
// dtype-dispatched external load (flag wave-uniform -> scalar branch)
__device__ __forceinline__ float ldf(const void* p, size_t i, bool f32) {
  return f32 ? ((const float*)p)[i] : bf2f(((const u16*)p)[i]);
}
__device__ __forceinline__ u64 minu64(u64 a, u64 b) { return a < b ? a : b; }

// per-wave dtype detect: every wave reads pos[0..63] as f32 and ballots the
// "plausible float" test -- wave-uniform result, no global flag roundtrip.
__device__ __forceinline__ bool wave_detect(const void* pos) {
  float a = fabsf(((const float*)pos)[threadIdx.x & 63]);
  bool ok = (a > 1.0e-3f && a < 100.0f);
  unsigned long long m = __ballot(ok);
  return __popcll(m) >= 32;
}

// ---------------- workspace layout (bytes) ----------------
#define NBR_OFF   ((size_t)0)                       // int32 [163840]       655,360
#define L4P_OFF   (((size_t)(1u << 20)) + 131072)   // f32 [8][15][240]     115,200
#define C1T_OFF   (((size_t)(1u << 20)) + 524288)   // fp16 [64][64]          8,192
#define C2T_OFF   (((size_t)(1u << 20)) + 589824)   // fp16 [128][1120]     286,720
#define C3T_OFF   ((size_t)(2u << 20))              // fp16 [1024][2240]  4,587,520
#define C4T_OFF   ((size_t)(7u << 20))              // f32  [40][38400]   6,144,000
#define PMAX_OFF  ((size_t)(13u << 20))             // f32 [256][1024]    1,048,576
#define PSUM_OFF  ((size_t)(14u << 20))             // f32 [256][1024]    1,048,576
#define X1_OFF    ((size_t)(15u << 20))             // fp16 [8192][128]   2,097,152
// peak ~17 MB (h1 eliminated)

// ---------------- tkan transpose body (compile-time constants) --------------
// Angle-major k-order: p < 4*NA: aa=p>>2, g=(p&3)+1 ; p in [4*NA,5*NA):
// aa=p-4*NA, g=5. f = 2*p + part. Pad f>=Kt with zeros.
template <int DOUT, int NW, int WW, int KPAD, int OUTF32>
__device__ __forceinline__ void tkan_body(const void* __restrict__ src,
                                          void* __restrict__ dst,
                                          int id, bool f32) {
  constexpr int NA = NW * WW;
  constexpr int Kt = NA * 10;
  constexpr int OS = NA * 5;
  const int o = id / KPAD, f = id % KPAD;   // literal KPAD -> magic multiply
  float v = 0.f;
  if (f < Kt) {
    const int part = f & 1, p = f >> 1;
    int aa, gg;
    if (p < 4 * NA) { aa = p >> 2;      gg = p & 3; }
    else            { aa = p - 4 * NA;  gg = 4;     }
    const int i = aa % WW, w = aa / WW;     // literal WW
    size_t sidx = (size_t)part * (DOUT * OS) + (size_t)o * OS +
                  (size_t)w * (WW * 5) + i * 5 + gg;
    v = ldf(src, sidx, f32);
  }
  if (OUTF32) ((float*)dst)[id] = v;
  else        ((u16*)dst)[id] = f2h(v);
}

// ---------------- merged prep: knn [0,2048) + coeff transpose [2048,17584) --
__global__ __launch_bounds__(256) void prep_kernel(
    const void* __restrict__ pos, int* __restrict__ nbr,
    const void* __restrict__ s1, void* __restrict__ d1,
    const void* __restrict__ s2, void* __restrict__ d2,
    const void* __restrict__ s3, void* __restrict__ d3,
    const void* __restrict__ s4, void* __restrict__ d4) {
  __shared__ float px[1024], py[1024], pz[1024];
  const bool f32 = wave_detect(pos);
  const int blk = blockIdx.x;
  const int t = threadIdx.x;

  if (blk >= 2048) {                         // ---- coeff transpose part ----
    const int tb = blk - 2048;
    if (tb < 16) {
      tkan_body<64, 2, 3, 64, 0>(s1, d1, tb * 256 + t, f32);
    } else if (tb < 576) {
      tkan_body<128, 7, 16, 1120, 0>(s2, d2, (tb - 16) * 256 + t, f32);
    } else if (tb < 9536) {
      tkan_body<1024, 7, 32, 2240, 0>(s3, d3, (tb - 576) * 256 + t, f32);
    } else {
      tkan_body<40, 15, 256, 38400, 1>(s4, d4, (tb - 9536) * 256 + t, f32);
    }
    return;
  }

  // ---- brute-force kNN: one wave per query ----
  const int b = blk >> 8;                    // cloud [0,8)
  const int x = blk & 255;                   // query group [0,256)
  const int base = b << 10;
  for (int j = t; j < 1024; j += 256) {
    size_t pidx = (size_t)(base + j) * 3;
    px[j] = ldf(pos, pidx, f32);
    py[j] = ldf(pos, pidx + 1, f32);
    pz[j] = ldf(pos, pidx + 2, f32);
  }
  __syncthreads();
  const int wv = t >> 6, lane = t & 63;
  const int q = x * 4 + wv;
  const float qx = px[q], qy = py[q], qz = pz[q];
  u64 key[16];
#pragma unroll
  for (int s = 0; s < 16; ++s) {
    const int j = s * 64 + lane;
    float dx = qx - px[j], dy = qy - py[j], dz = qz - pz[j];
    float d = __fadd_rn(__fadd_rn(__fmul_rn(dx, dx), __fmul_rn(dy, dy)),
                        __fmul_rn(dz, dz));
    key[s] = (j == q) ? ~0ull
                      : ((((u64)__float_as_uint(d)) << 32) | (u32)j);
  }
  const int obase = (base + q) * 20;
  for (int k = 0; k < 20; ++k) {
    u64 m = key[0];
#pragma unroll
    for (int s = 1; s < 16; ++s) m = minu64(m, key[s]);
#pragma unroll
    for (int off = 32; off >= 1; off >>= 1) {
      u32 lo = (u32)m, hi = (u32)(m >> 32);
      lo = __shfl_xor(lo, off, 64);
      hi = __shfl_xor(hi, off, 64);
      m = minu64(m, (((u64)hi) << 32) | lo);
    }
    if (lane == 0) nbr[obase + k] = (int)(u32)m;
#pragma unroll
    for (int s = 0; s < 16; ++s)
      if (key[s] == m) key[s] = ~0ull;  // idx embedded -> unique, safe
  }
}

// ---------------- MFMA KAN layer, LDS double-buffered B ---------------------
// L==2 additionally embeds the L1 layer: each wave computes its 80 slab rows
// of h1 in-place (acc1[5][4], NCH1=2, B direct from 8KB L1-resident c1t).
// Per chunk: 256 threads each load NPC 16B pieces of next chunk's B, build
// NEXT chunk's A fragments (pipelined one ahead), MFMA current chunk from
// Bbuf ds_read_b128 + last iter's af, then ds_write+barrier.
// PSTH=DIN+4 halves: lane stride -> 16 distinct banks.
template <int L>
__global__ __launch_bounds__(256, (L == 2) ? 2 : 3) void kan_kernel(
    const void* __restrict__ in_, const int* __restrict__ nbr,
    const void* __restrict__ pos, const u16* __restrict__ ct,
    const void* __restrict__ bias, void* __restrict__ out_,
    float* __restrict__ pmax, float* __restrict__ psum,
    const u16* __restrict__ ct1, const void* __restrict__ bias1) {
  constexpr int W    = (L == 2) ? 16  : 32;
  constexpr int S    = (L == 2) ? 8   : 16;
  constexpr int DIN  = (L == 2) ? 64  : 128;
  constexpr int NT   = (L == 2) ? 128 : 64;         // L2: full 128-col tile
  constexpr int NW   = (DIN - W) / S + 1;
  constexpr int NA   = NW * W;                      // angles
  constexpr int NPAIR = NA * 5;
  constexpr int S1P  = NA * 4;                      // section-1 pairs (g=1..4)
  constexpr int KROW  = NPAIR * 2;                  // ct row stride
  constexpr int NCH   = KROW / 32;                  // L2:35(odd!)  L3:70
  constexpr int NB    = NT / 16;                    // 8 or 4
  constexpr int RW    = (L == 2) ? 80 : 32;         // rows per wave
  constexpr int MB    = RW / 16;
  constexpr int PSTH  = DIN + 4;                    // slab stride (halves)
  constexpr int LGW   = (W == 16) ? 4 : 5;          // log2(W)
  constexpr int BCS   = NT * 8 + 8;                 // Bbuf halves per part
  constexpr int BBS   = 4 * BCS;                    // Bbuf halves per buffer
  constexpr int NPC   = NT / 64;                    // 16B B-pieces per thread

  __shared__ float hamS[W];
  __shared__ float wT1[(L == 2) ? 32 : 1];          // embedded-L1 tables
  __shared__ int   hT1[(L == 2) ? 32 : 1];
  __shared__ u16   slab[4 * RW * PSTH];
  __shared__ u16   Bbuf[2 * BBS];                   // [buf][part(4)][BCS]

  const bool f32 = wave_detect(pos);
  const u16* inH = (const u16*)in_;
  const int t = threadIdx.x;
  if (t < W) hamS[t] = 0.54f - 0.46f * cospif(2.0f * (float)t / (float)(W - 1));
  if constexpr (L == 2) {
    // embedded-L1 angle tables (W1=3, NPAIR1=30, S1P1=24)
    if (t < 32) {
      float wv_ = 0.f; int hx = 0;
      if (t < 30) {
        int aa, gg;
        if (t < 24) { aa = t >> 2;  gg = t & 3; }
        else        { aa = t - 24;  gg = 4;     }
        int i = aa % 3;
        float hm = 0.54f - 0.46f * cospif((float)i);   // 2*i/(3-1) = i
        wv_ = hm * (float)(gg + 1);
        hx = aa;
      }
      wT1[t] = wv_; hT1[t] = hx;
    }
  }

  // ---- block index: L3 uses XCD-aware swizzle (id%8-equal share 2 slices) --
  int tile, ncol0;
  if constexpr (L == 3) {
    const int id = blockIdx.x;                      // 1024 linear
    tile = (id >> 3) & 63;
    ncol0 = ((((id & 7) << 1) | (id >> 9))) * NT;
  } else {
    tile = blockIdx.x;
    ncol0 = 0;
  }
  const int lane = t & 63, wv = t >> 6;
  const int m16 = lane & 15, kb = lane >> 4;
  const int rowbase = tile * (4 * RW) + wv * RW;
  u16* myslab = &slab[wv * RW * PSTH];

  // B staging indices: piece p covers col=p>>2, part=p&3 (16B each)
  const u16* srcB[NPC];
  int sdst[NPC];
#pragma unroll
  for (int p_ = 0; p_ < NPC; ++p_) {
    const int pid = t + p_ * 256;
    const int scol = pid >> 2, spart = pid & 3;
    srcB[p_] = ct + (size_t)(ncol0 + scol) * KROW + spart * 8;
    sdst[p_] = spart * BCS + scol * 8;
  }

  // ---- stage wave-private fp16 slab from global input (L3 only) ----
  if constexpr (L == 3) {
    constexpr int F4R = DIN / 4;
    constexpr int TOT = RW * F4R;
    for (int i = lane; i < TOT; i += 64) {
      const int r = i / F4R, c4 = i % F4R;
      *(uint2*)(myslab + r * PSTH + c4 * 4) =
          *(const uint2*)(inH + (size_t)(rowbase + r) * DIN + c4 * 4);
    }
  }

  // ---- prologue: stage B chunk 0 ----
#pragma unroll
  for (int p_ = 0; p_ < NPC; ++p_) {
    const uint4 v = *(const uint4*)srcB[p_];
    *(uint4*)(Bbuf + sdst[p_]) = v;
  }
  __syncthreads();  // covers hamS/wT1/hT1 + Bbuf[0]

  // ---- embedded L1 phase (L==2): compute this wave's 80 slab rows of h1 ---
  if constexpr (L == 2) {
    f32x4 acc1[5][4];
#pragma unroll
    for (int mb = 0; mb < 5; ++mb)
#pragma unroll
      for (int nb = 0; nb < 4; ++nb) {
        acc1[mb][nb][0] = 0.f; acc1[mb][nb][1] = 0.f;
        acc1[mb][nb][2] = 0.f; acc1[mb][nb][3] = 0.f;
      }
#pragma unroll
    for (int c = 0; c < 2; ++c) {            // NCH1 = 2 (K padded 60->64)
      const int pg0 = c * 16 + kb * 4;
      float wm[4]; int hx[4]; bool val[4];
#pragma unroll
      for (int u = 0; u < 4; ++u) {
        const int pg = pg0 + u;
        wm[u] = wT1[pg]; hx[u] = hT1[pg]; val[u] = (pg < 30);
      }
      half8 af1[5];
#pragma unroll
      for (int mb = 0; mb < 5; ++mb) {
        const int row = rowbase + mb * 16 + m16;
        const int pt = row / 20;
        const int cloud = pt >> 10, ci = pt & 1023;
        const int cb = cloud << 10;
        const int jl = nbr[row];
#pragma unroll
        for (int u = 0; u < 4; ++u) {
          float cs = 0.f, sn = 0.f;
          if (val[u]) {
            const int aa = hx[u];
            float v;
            if (aa < 3) {
              v = ldf(pos, (size_t)(cb + ci) * 3 + aa, f32);
            } else {
              const int cc2 = aa - 3;
              v = ldf(pos, (size_t)(cb + jl) * 3 + cc2, f32) -
                  ldf(pos, (size_t)(cb + ci) * 3 + cc2, f32);
            }
            const float ang = v * wm[u];
            cs = __cosf(ang); sn = __sinf(ang);
          }
          af1[mb][2 * u]     = (_Float16)cs;
          af1[mb][2 * u + 1] = (_Float16)sn;
        }
      }
      // B direct from c1t [64 cols][64 k] -- 8KB, L1-cache-resident
#pragma unroll
      for (int nb = 0; nb < 4; ++nb) {
        const half8 bv = *(const half8*)(ct1 + (nb * 16 + m16) * 64 +
                                         c * 32 + kb * 8);
#pragma unroll
        for (int mb = 0; mb < 5; ++mb)
          acc1[mb][nb] = __builtin_amdgcn_mfma_f32_16x16x32_f16(
              af1[mb], bv, acc1[mb][nb], 0, 0, 0);
      }
    }
    // write h1 rows into wave-private slab (proven C-layout transform)
#pragma unroll
    for (int mb = 0; mb < 5; ++mb)
#pragma unroll
      for (int nb = 0; nb < 4; ++nb) {
        const float bsv = ldf(bias1, nb * 16 + m16, f32);
#pragma unroll
        for (int r = 0; r < 4; ++r)
          myslab[(mb * 16 + kb * 4 + r) * PSTH + nb * 16 + m16] =
              f2h(acc1[mb][nb][r] + bsv);
      }
    // same-wave LDS RAW below (compiler orders); no barrier needed
  }

  f32x4 acc[MB][NB];
#pragma unroll
  for (int mb = 0; mb < MB; ++mb)
#pragma unroll
    for (int nb = 0; nb < NB; ++nb) {
      acc[mb][nb][0] = 0.f; acc[mb][nb][1] = 0.f;
      acc[mb][nb][2] = 0.f; acc[mb][nb][3] = 0.f;
    }

  // ---- A-fragment builder for chunk c (reads slab only) ----
  auto build_af = [&](int c, half8* af) {
    const int pg0 = c * 16 + kb * 4;
    if (pg0 < S1P) {
      // section 1: one angle, g=1..4 -> Chebyshev recurrence
      const int aa = pg0 >> 2;
      const int i = aa & (W - 1), w = aa >> LGW;
      const int hidx = S * w + i;
      const float hm = hamS[i];
#pragma unroll
      for (int mb = 0; mb < MB; ++mb) {
        const u16* rp = myslab + (mb * 16 + m16) * PSTH;
        const float th = h2f(rp[hidx]) * hm;
        const float c1 = __cosf(th), s1 = __sinf(th);
        const float tc = 2.0f * c1;
        const float c2 = tc * c1 - 1.0f, s2 = tc * s1;
        const float c3 = tc * c2 - c1,   s3 = tc * s2 - s1;
        const float c4 = tc * c3 - c2,   s4 = tc * s3 - s2;
        af[mb][0] = (_Float16)c1; af[mb][1] = (_Float16)s1;
        af[mb][2] = (_Float16)c2; af[mb][3] = (_Float16)s2;
        af[mb][4] = (_Float16)c3; af[mb][5] = (_Float16)s3;
        af[mb][6] = (_Float16)c4; af[mb][7] = (_Float16)s4;
      }
    } else {
      // section 2: g=5 tail, 4 distinct angles, direct cos/sin
      const int q0 = pg0 - S1P;
      float wm[4]; int hx[4];
#pragma unroll
      for (int u = 0; u < 4; ++u) {
        const int aa = q0 + u;
        const int i = aa & (W - 1), w = aa >> LGW;
        hx[u] = S * w + i;
        wm[u] = hamS[i] * 5.0f;
      }
#pragma unroll
      for (int mb = 0; mb < MB; ++mb) {
        const u16* rp = myslab + (mb * 16 + m16) * PSTH;
#pragma unroll
        for (int u = 0; u < 4; ++u) {
          const float ang = h2f(rp[hx[u]]) * wm[u];
          af[mb][2 * u]     = (_Float16)__cosf(ang);
          af[mb][2 * u + 1] = (_Float16)__sinf(ang);
        }
      }
    }
  };

  // ---- one pipelined chunk: uses afc (built last iter), builds afn ----
  auto step = [&](int c, half8* afc, half8* afn) {
    const bool havenext = (c + 1 < NCH);
    // issue next chunk's B global load (overlaps everything below)
    uint4 bnext[NPC];
    if (havenext) {
#pragma unroll
      for (int p_ = 0; p_ < NPC; ++p_)
        bnext[p_] = *(const uint4*)(srcB[p_] + (c + 1) * 32);
    }
    // build NEXT chunk's A fragments; MFMA below consumes afc from LAST
    // iter -> trans chain off the MFMA critical path
    if (havenext) build_af(c + 1, afn);
    // MFMA: bv loaded per-nb (keep live set small -- R24 spill lesson)
    const u16* bb = Bbuf + (c & 1) * BBS + kb * BCS;
#pragma unroll
    for (int nb = 0; nb < NB; ++nb) {
      const half8 bv = *(const half8*)(bb + (nb * 16 + m16) * 8);
#pragma unroll
      for (int mb = 0; mb < MB; ++mb)
        acc[mb][nb] = __builtin_amdgcn_mfma_f32_16x16x32_f16(
            afc[mb], bv, acc[mb][nb], 0, 0, 0);
    }
    // commit next chunk's B to LDS, barrier
    if (havenext) {
#pragma unroll
      for (int p_ = 0; p_ < NPC; ++p_)
        *(uint4*)(Bbuf + ((c + 1) & 1) * BBS + sdst[p_]) = bnext[p_];
      __syncthreads();
    }
  };

  half8 afA[MB], afB[MB];
  build_af(0, afA);
  constexpr int NCH2 = (NCH / 2) * 2;  // even part: L2 34, L3 70
  for (int c = 0; c < NCH2; c += 2) {
    step(c, afA, afB);
    step(c + 1, afB, afA);
  }
  if constexpr ((NCH & 1) != 0) {
    // odd tail (L2: c=34). step(NCH2-1, afB, afA) built afA=af(NCH-1);
    // buf[(NCH-1)&1] was committed+barriered there. Consume it.
    step(NCH - 1, afA, afB);
  }

  // ---- fused epilogues (C layout: row=kb*4+r, col=m16 within 16x16) ----
  if constexpr (L == 2) {
    // C-tile (80x128) -> dead slab (stride PSTH) in two 64-col passes,
    // maxpool over 20 rows each pass, write x1 fp16
    u16* st = myslab;
    const int pbase = tile * 16 + wv * 4;       // 4 points per wave
#pragma unroll
    for (int h = 0; h < 2; ++h) {
#pragma unroll
      for (int mb = 0; mb < MB; ++mb)
#pragma unroll
        for (int nb4 = 0; nb4 < 4; ++nb4) {
          const int nb = h * 4 + nb4;
          const float bsv = ldf(bias, nb * 16 + m16, f32);
#pragma unroll
          for (int r = 0; r < 4; ++r)
            st[(mb * 16 + kb * 4 + r) * PSTH + nb4 * 16 + m16] =
                f2h(acc[mb][nb][r] + bsv);
        }
#pragma unroll
      for (int j = 0; j < 4; ++j) {
        float m = -3.0e38f;
#pragma unroll
        for (int k = 0; k < 20; ++k)
          m = fmaxf(m, h2f(st[(j * 20 + k) * PSTH + lane]));
        ((u16*)out_)[(size_t)(pbase + j) * 128 + h * 64 + lane] = f2h(m);
      }
    }
  } else {
    // in-register max/sum over 32 rows + kb butterfly -> pmax/psum partials
    const int chunk = rowbase >> 5;
#pragma unroll
    for (int nb = 0; nb < NB; ++nb) {
      const int col = ncol0 + nb * 16 + m16;
      const float bsv = ldf(bias, col, f32);
      float m = -3.0e38f, s = 0.f;
#pragma unroll
      for (int mb = 0; mb < MB; ++mb)
#pragma unroll
        for (int r = 0; r < 4; ++r) {
          const float v = acc[mb][nb][r] + bsv;
          m = fmaxf(m, v); s += v;
        }
#pragma unroll
      for (int off = 16; off <= 32; off <<= 1) {
        m = fmaxf(m, __shfl_xor(m, off, 64));
        s += __shfl_xor(s, off, 64);
      }
      if (kb == 0) {
        pmax[(size_t)chunk * 1024 + col] = m;
        psum[(size_t)chunk * 1024 + col] = s;
      }
    }
  }
}

// ---------------- layer 4 partials (seg reduce fused in) --------------------
// c4t GLOBAL layout (angle-major): window w section-1 (g1..4 quads) at
// o*38400 + w*2048 ; g5 tail at o*38400 + 30720 + w*512.
// grid (15,8,2): z splits the 6 dot slices into 2x3 (240 blocks).
__global__ __launch_bounds__(256) void l4_kernel(const float* __restrict__ pmax,
                                                 const float* __restrict__ psum,
                                                 const float* __restrict__ c4t,
                                                 float* __restrict__ part) {
  __shared__ float F[2560];
  const int t = threadIdx.x;
  const int w = blockIdx.x, b = blockIdx.y, z = blockIdx.z;
  // fused segment combine (same reduce order as former seg2)
  const int ch = w * 128 + t;
  float xv;
  if (ch < 1024) {
    float m = -3.0e38f;
    for (int rc = 0; rc < 32; ++rc)
      m = fmaxf(m, pmax[(size_t)(b * 32 + rc) * 1024 + ch]);
    xv = m;
  } else {
    const int cc = ch - 1024;
    float s = 0.f;
    for (int rc = 0; rc < 32; ++rc)
      s += psum[(size_t)(b * 32 + rc) * 1024 + cc];
    xv = s * (1.0f / 1024.0f);
  }
  const float hm = 0.54f - 0.46f * cospif(2.0f * (float)t / 255.0f);
  const float aa = xv * hm;
  const float c1 = __cosf(aa), s1 = __sinf(aa);
  const float tc = 2.0f * c1;
  const float c2 = tc * c1 - 1.0f, s2 = tc * s1;
  const float c3 = tc * c2 - c1,   s3 = tc * s2 - s1;
  const float c4 = tc * c3 - c2,   s4 = tc * s3 - s2;
  const float a5 = aa * 5.0f;
  F[t * 8]     = c1; F[t * 8 + 1] = s1;
  F[t * 8 + 2] = c2; F[t * 8 + 3] = s2;
  F[t * 8 + 4] = c3; F[t * 8 + 5] = s3;
  F[t * 8 + 6] = c4; F[t * 8 + 7] = s4;
  F[2048 + t * 2]     = __cosf(a5);
  F[2048 + t * 2 + 1] = __sinf(a5);
  __syncthreads();
  if (t < 120) {
    const int o = t % 40, sl = t / 40;          // sl in [0,3)
    const int s = z * 3 + sl;                   // s in [0,6)
    const int f0 = s * 432;
    const int f1 = (f0 + 432 < 2560) ? (f0 + 432) : 2560;
    const float* cp1 = c4t + (size_t)o * 38400 + w * 2048;          // sec 1
    const float* cp2 = c4t + (size_t)o * 38400 + 30720 + w * 512;   // g5 tail
    float acc = 0.f;
    for (int f = f0; f < f1; f += 4) {   // 2048 boundary is float4-aligned
      const float* cpf = (f < 2048) ? (cp1 + f) : (cp2 + (f - 2048));
      const float4 cv = *(const float4*)cpf;
      const float4 fa = *(const float4*)&F[f];
      acc += fa.x * cv.x + fa.y * cv.y + fa.z * cv.z + fa.w * cv.w;
    }
    part[((b * 15 + w) * 6 + s) * 40 + o] = acc;
  }
}

__global__ void outred_kernel(const float* __restrict__ part,
                              const void* __restrict__ b4,
                              const void* __restrict__ pos,
                              void* __restrict__ outp) {
  int t = threadIdx.x;
  const bool f32 = wave_detect(pos);
  if (t >= 320) return;
  int b = t / 40, o = t % 40;
  float s = ldf(b4, o, f32);
  for (int w = 0; w < 15; ++w)
#pragma unroll
    for (int sl = 0; sl < 6; ++sl)
      s += part[((b * 15 + w) * 6 + sl) * 40 + o];
  if (f32) ((float*)outp)[t] = s;
  else     ((u16*)outp)[t] = f2bfr(s);
}

// ---------------------------------------------------------------------------
extern "C" void kernel_launch(void* const* d_in, const int* in_sizes, int n_in,
                              void* d_out, int out_size, void* d_ws,
                              size_t ws_size, hipStream_t stream) {
  (void)in_sizes; (void)n_in; (void)out_size; (void)ws_size;
  const void* pos = d_in[0];
  // d_in[1] = batch (int32) -- clouds are sorted equal-size, used implicitly
  const void* c1 = d_in[2];
  const void* b1 = d_in[3];
  const void* c2 = d_in[4];
  const void* b2 = d_in[5];
  const void* c3 = d_in[6];
  const void* b3 = d_in[7];
  const void* c4 = d_in[8];
  const void* b4 = d_in[9];

  char* ws = (char*)d_ws;
  int* nbr   = (int*)(ws + NBR_OFF);
  float* l4p = (float*)(ws + L4P_OFF);
  u16* c1t   = (u16*)(ws + C1T_OFF);
  u16* c2t   = (u16*)(ws + C2T_OFF);
  u16* c3t   = (u16*)(ws + C3T_OFF);
  float* c4t = (float*)(ws + C4T_OFF);
  float* pmax = (float*)(ws + PMAX_OFF);
  float* psum = (float*)(ws + PSUM_OFF);
  u16* x1    = (u16*)(ws + X1_OFF);

  // merged prep: knn (blocks [0,2048)) + coeff transpose ([2048,17584))
  prep_kernel<<<17584, 256, 0, stream>>>(pos, nbr, c1, c1t, c2, c2t,
                                         c3, c3t, c4, c4t);

  // L1+L2 fused: 512 blocks x 320 rows; each wave computes its 80 h1 rows
  // in-slab (embedded L1) then runs the NT=128 L2 + maxpool
  kan_kernel<2><<<dim3(512), 256, 0, stream>>>(nullptr, nbr, pos, c2t,
                                               b2, x1, nullptr, nullptr,
                                               c1t, b1);
  // L3 fused segment partials: 1024 linear blocks, XCD-swizzled inside
  kan_kernel<3><<<1024, 256, 0, stream>>>(x1, nullptr, pos, c3t,
                                          b3, nullptr, pmax, psum,
                                          nullptr, nullptr);

  l4_kernel<<<dim3(15, 8, 2), 256, 0, stream>>>(pmax, psum, c4t, l4p);
  outred_kernel<<<1, 320, 0, stream>>>(l4p, b4, pos, d_out);
}

// Round 15
// 280.447 us; speedup vs baseline: 1.0145x; 1.0013x over previous
//
#include <hip/hip_runtime.h>

// ---------------------------------------------------------------------------
// STFT-Fourier-KAN DGCNN on MI355X.
// R32/R34 (278-281us, BEST, reproduced): kan<1> fused into kan<2>, knn+tkan
// merged, l4 z-split. R33 lesson: boundary removal only pays between
// GPU-FILLING kernels. kan<2>~77 / kan<3>~75 plateaus structural.
// R35: delete the c4 transpose (6000 of prep's 17584 blocks + 12.2MB
// scattered round trip). c4's natural [part][o][w][i][g] layout is already
// contiguous in (i,g) per (part,o,w) -- 1280 floats per part -- so l4
// builds F as [part][i][g] (same 2560 values, relabeled) and dots two
// contiguous float4-aligned segments directly from raw c4 (dtype-dispatched
// float4 / ushort4+bf2f). prep grid 17584->11584. Everything else
// byte-identical to R34.
// ---------------------------------------------------------------------------

typedef unsigned short u16;
typedef unsigned int   u32;
typedef unsigned long long u64;
typedef __attribute__((ext_vector_type(8))) _Float16 half8;
typedef __attribute__((ext_vector_type(4))) float f32x4;

__device__ __forceinline__ float bf2f(u16 u) {
  u32 v = ((u32)u) << 16;
  return __uint_as_float(v);
}
__device__ __forceinline__ u16 f2bfr(float f) {  // bf16 round-to-nearest-even
  u32 x = __float_as_uint(f);
  u32 r = x + 0x7FFFu + ((x >> 16) & 1u);
  return (u16)(r >> 16);
}
__device__ __forceinline__ u16 f2h(float f) {    // fp16 RTN bits
  _Float16 h = (_Float16)f;
  u16 r;
  __builtin_memcpy(&r, &h, 2);
  return r;
}
__device__ __forceinline__ float h2f(u16 u) {
  _Float16 h;
  __builtin_memcpy(&h, &u, 2);
  return (float)h;
}
// dtype-dispatched external load (flag wave-uniform -> scalar branch)
__device__ __forceinline__ float ldf(const void* p, size_t i, bool f32) {
  return f32 ? ((const float*)p)[i] : bf2f(((const u16*)p)[i]);
}
__device__ __forceinline__ u64 minu64(u64 a, u64 b) { return a < b ? a : b; }

// per-wave dtype detect: every wave reads pos[0..63] as f32 and ballots the
// "plausible float" test -- wave-uniform result, no global flag roundtrip.
__device__ __forceinline__ bool wave_detect(const void* pos) {
  float a = fabsf(((const float*)pos)[threadIdx.x & 63]);
  bool ok = (a > 1.0e-3f && a < 100.0f);
  unsigned long long m = __ballot(ok);
  return __popcll(m) >= 32;
}

// ---------------- workspace layout (bytes) ----------------
#define NBR_OFF   ((size_t)0)                       // int32 [163840]       655,360
#define L4P_OFF   (((size_t)(1u << 20)) + 131072)   // f32 [8][15][240]     115,200
#define C1T_OFF   (((size_t)(1u << 20)) + 524288)   // fp16 [64][64]          8,192
#define C2T_OFF   (((size_t)(1u << 20)) + 589824)   // fp16 [128][1120]     286,720
#define C3T_OFF   ((size_t)(2u << 20))              // fp16 [1024][2240]  4,587,520
#define PMAX_OFF  ((size_t)(13u << 20))             // f32 [256][1024]    1,048,576
#define PSUM_OFF  ((size_t)(14u << 20))             // f32 [256][1024]    1,048,576
#define X1_OFF    ((size_t)(15u << 20))             // fp16 [8192][128]   2,097,152
// peak ~17 MB (h1, c4t eliminated)

// ---------------- tkan transpose body (compile-time constants) --------------
// Angle-major k-order: p < 4*NA: aa=p>>2, g=(p&3)+1 ; p in [4*NA,5*NA):
// aa=p-4*NA, g=5. f = 2*p + part. Pad f>=Kt with zeros.
template <int DOUT, int NW, int WW, int KPAD, int OUTF32>
__device__ __forceinline__ void tkan_body(const void* __restrict__ src,
                                          void* __restrict__ dst,
                                          int id, bool f32) {
  constexpr int NA = NW * WW;
  constexpr int Kt = NA * 10;
  constexpr int OS = NA * 5;
  const int o = id / KPAD, f = id % KPAD;   // literal KPAD -> magic multiply
  float v = 0.f;
  if (f < Kt) {
    const int part = f & 1, p = f >> 1;
    int aa, gg;
    if (p < 4 * NA) { aa = p >> 2;      gg = p & 3; }
    else            { aa = p - 4 * NA;  gg = 4;     }
    const int i = aa % WW, w = aa / WW;     // literal WW
    size_t sidx = (size_t)part * (DOUT * OS) + (size_t)o * OS +
                  (size_t)w * (WW * 5) + i * 5 + gg;
    v = ldf(src, sidx, f32);
  }
  if (OUTF32) ((float*)dst)[id] = v;
  else        ((u16*)dst)[id] = f2h(v);
}

// ---------------- merged prep: knn [0,2048) + coeff transpose [2048,11584) --
__global__ __launch_bounds__(256) void prep_kernel(
    const void* __restrict__ pos, int* __restrict__ nbr,
    const void* __restrict__ s1, void* __restrict__ d1,
    const void* __restrict__ s2, void* __restrict__ d2,
    const void* __restrict__ s3, void* __restrict__ d3) {
  __shared__ float px[1024], py[1024], pz[1024];
  const bool f32 = wave_detect(pos);
  const int blk = blockIdx.x;
  const int t = threadIdx.x;

  if (blk >= 2048) {                         // ---- coeff transpose part ----
    const int tb = blk - 2048;
    if (tb < 16) {
      tkan_body<64, 2, 3, 64, 0>(s1, d1, tb * 256 + t, f32);
    } else if (tb < 576) {
      tkan_body<128, 7, 16, 1120, 0>(s2, d2, (tb - 16) * 256 + t, f32);
    } else {
      tkan_body<1024, 7, 32, 2240, 0>(s3, d3, (tb - 576) * 256 + t, f32);
    }
    return;
  }

  // ---- brute-force kNN: one wave per query ----
  const int b = blk >> 8;                    // cloud [0,8)
  const int x = blk & 255;                   // query group [0,256)
  const int base = b << 10;
  for (int j = t; j < 1024; j += 256) {
    size_t pidx = (size_t)(base + j) * 3;
    px[j] = ldf(pos, pidx, f32);
    py[j] = ldf(pos, pidx + 1, f32);
    pz[j] = ldf(pos, pidx + 2, f32);
  }
  __syncthreads();
  const int wv = t >> 6, lane = t & 63;
  const int q = x * 4 + wv;
  const float qx = px[q], qy = py[q], qz = pz[q];
  u64 key[16];
#pragma unroll
  for (int s = 0; s < 16; ++s) {
    const int j = s * 64 + lane;
    float dx = qx - px[j], dy = qy - py[j], dz = qz - pz[j];
    float d = __fadd_rn(__fadd_rn(__fmul_rn(dx, dx), __fmul_rn(dy, dy)),
                        __fmul_rn(dz, dz));
    key[s] = (j == q) ? ~0ull
                      : ((((u64)__float_as_uint(d)) << 32) | (u32)j);
  }
  const int obase = (base + q) * 20;
  for (int k = 0; k < 20; ++k) {
    u64 m = key[0];
#pragma unroll
    for (int s = 1; s < 16; ++s) m = minu64(m, key[s]);
#pragma unroll
    for (int off = 32; off >= 1; off >>= 1) {
      u32 lo = (u32)m, hi = (u32)(m >> 32);
      lo = __shfl_xor(lo, off, 64);
      hi = __shfl_xor(hi, off, 64);
      m = minu64(m, (((u64)hi) << 32) | lo);
    }
    if (lane == 0) nbr[obase + k] = (int)(u32)m;
#pragma unroll
    for (int s = 0; s < 16; ++s)
      if (key[s] == m) key[s] = ~0ull;  // idx embedded -> unique, safe
  }
}

// ---------------- MFMA KAN layer, LDS double-buffered B ---------------------
// L==2 additionally embeds the L1 layer: each wave computes its 80 slab rows
// of h1 in-place (acc1[5][4], NCH1=2, B direct from 8KB L1-resident c1t).
// Per chunk: 256 threads each load NPC 16B pieces of next chunk's B, build
// NEXT chunk's A fragments (pipelined one ahead), MFMA current chunk from
// Bbuf ds_read_b128 + last iter's af, then ds_write+barrier.
// PSTH=DIN+4 halves: lane stride -> 16 distinct banks.
template <int L>
__global__ __launch_bounds__(256, (L == 2) ? 2 : 3) void kan_kernel(
    const void* __restrict__ in_, const int* __restrict__ nbr,
    const void* __restrict__ pos, const u16* __restrict__ ct,
    const void* __restrict__ bias, void* __restrict__ out_,
    float* __restrict__ pmax, float* __restrict__ psum,
    const u16* __restrict__ ct1, const void* __restrict__ bias1) {
  constexpr int W    = (L == 2) ? 16  : 32;
  constexpr int S    = (L == 2) ? 8   : 16;
  constexpr int DIN  = (L == 2) ? 64  : 128;
  constexpr int NT   = (L == 2) ? 128 : 64;         // L2: full 128-col tile
  constexpr int NW   = (DIN - W) / S + 1;
  constexpr int NA   = NW * W;                      // angles
  constexpr int NPAIR = NA * 5;
  constexpr int S1P  = NA * 4;                      // section-1 pairs (g=1..4)
  constexpr int KROW  = NPAIR * 2;                  // ct row stride
  constexpr int NCH   = KROW / 32;                  // L2:35(odd!)  L3:70
  constexpr int NB    = NT / 16;                    // 8 or 4
  constexpr int RW    = (L == 2) ? 80 : 32;         // rows per wave
  constexpr int MB    = RW / 16;
  constexpr int PSTH  = DIN + 4;                    // slab stride (halves)
  constexpr int LGW   = (W == 16) ? 4 : 5;          // log2(W)
  constexpr int BCS   = NT * 8 + 8;                 // Bbuf halves per part
  constexpr int BBS   = 4 * BCS;                    // Bbuf halves per buffer
  constexpr int NPC   = NT / 64;                    // 16B B-pieces per thread

  __shared__ float hamS[W];
  __shared__ float wT1[(L == 2) ? 32 : 1];          // embedded-L1 tables
  __shared__ int   hT1[(L == 2) ? 32 : 1];
  __shared__ u16   slab[4 * RW * PSTH];
  __shared__ u16   Bbuf[2 * BBS];                   // [buf][part(4)][BCS]

  const bool f32 = wave_detect(pos);
  const u16* inH = (const u16*)in_;
  const int t = threadIdx.x;
  if (t < W) hamS[t] = 0.54f - 0.46f * cospif(2.0f * (float)t / (float)(W - 1));
  if constexpr (L == 2) {
    // embedded-L1 angle tables (W1=3, NPAIR1=30, S1P1=24)
    if (t < 32) {
      float wv_ = 0.f; int hx = 0;
      if (t < 30) {
        int aa, gg;
        if (t < 24) { aa = t >> 2;  gg = t & 3; }
        else        { aa = t - 24;  gg = 4;     }
        int i = aa % 3;
        float hm = 0.54f - 0.46f * cospif((float)i);   // 2*i/(3-1) = i
        wv_ = hm * (float)(gg + 1);
        hx = aa;
      }
      wT1[t] = wv_; hT1[t] = hx;
    }
  }

  // ---- block index: L3 uses XCD-aware swizzle (id%8-equal share 2 slices) --
  int tile, ncol0;
  if constexpr (L == 3) {
    const int id = blockIdx.x;                      // 1024 linear
    tile = (id >> 3) & 63;
    ncol0 = ((((id & 7) << 1) | (id >> 9))) * NT;
  } else {
    tile = blockIdx.x;
    ncol0 = 0;
  }
  const int lane = t & 63, wv = t >> 6;
  const int m16 = lane & 15, kb = lane >> 4;
  const int rowbase = tile * (4 * RW) + wv * RW;
  u16* myslab = &slab[wv * RW * PSTH];

  // B staging indices: piece p covers col=p>>2, part=p&3 (16B each)
  const u16* srcB[NPC];
  int sdst[NPC];
#pragma unroll
  for (int p_ = 0; p_ < NPC; ++p_) {
    const int pid = t + p_ * 256;
    const int scol = pid >> 2, spart = pid & 3;
    srcB[p_] = ct + (size_t)(ncol0 + scol) * KROW + spart * 8;
    sdst[p_] = spart * BCS + scol * 8;
  }

  // ---- stage wave-private fp16 slab from global input (L3 only) ----
  if constexpr (L == 3) {
    constexpr int F4R = DIN / 4;
    constexpr int TOT = RW * F4R;
    for (int i = lane; i < TOT; i += 64) {
      const int r = i / F4R, c4 = i % F4R;
      *(uint2*)(myslab + r * PSTH + c4 * 4) =
          *(const uint2*)(inH + (size_t)(rowbase + r) * DIN + c4 * 4);
    }
  }

  // ---- prologue: stage B chunk 0 ----
#pragma unroll
  for (int p_ = 0; p_ < NPC; ++p_) {
    const uint4 v = *(const uint4*)srcB[p_];
    *(uint4*)(Bbuf + sdst[p_]) = v;
  }
  __syncthreads();  // covers hamS/wT1/hT1 + Bbuf[0]

  // ---- embedded L1 phase (L==2): compute this wave's 80 slab rows of h1 ---
  if constexpr (L == 2) {
    f32x4 acc1[5][4];
#pragma unroll
    for (int mb = 0; mb < 5; ++mb)
#pragma unroll
      for (int nb = 0; nb < 4; ++nb) {
        acc1[mb][nb][0] = 0.f; acc1[mb][nb][1] = 0.f;
        acc1[mb][nb][2] = 0.f; acc1[mb][nb][3] = 0.f;
      }
#pragma unroll
    for (int c = 0; c < 2; ++c) {            // NCH1 = 2 (K padded 60->64)
      const int pg0 = c * 16 + kb * 4;
      float wm[4]; int hx[4]; bool val[4];
#pragma unroll
      for (int u = 0; u < 4; ++u) {
        const int pg = pg0 + u;
        wm[u] = wT1[pg]; hx[u] = hT1[pg]; val[u] = (pg < 30);
      }
      half8 af1[5];
#pragma unroll
      for (int mb = 0; mb < 5; ++mb) {
        const int row = rowbase + mb * 16 + m16;
        const int pt = row / 20;
        const int cloud = pt >> 10, ci = pt & 1023;
        const int cb = cloud << 10;
        const int jl = nbr[row];
#pragma unroll
        for (int u = 0; u < 4; ++u) {
          float cs = 0.f, sn = 0.f;
          if (val[u]) {
            const int aa = hx[u];
            float v;
            if (aa < 3) {
              v = ldf(pos, (size_t)(cb + ci) * 3 + aa, f32);
            } else {
              const int cc2 = aa - 3;
              v = ldf(pos, (size_t)(cb + jl) * 3 + cc2, f32) -
                  ldf(pos, (size_t)(cb + ci) * 3 + cc2, f32);
            }
            const float ang = v * wm[u];
            cs = __cosf(ang); sn = __sinf(ang);
          }
          af1[mb][2 * u]     = (_Float16)cs;
          af1[mb][2 * u + 1] = (_Float16)sn;
        }
      }
      // B direct from c1t [64 cols][64 k] -- 8KB, L1-cache-resident
#pragma unroll
      for (int nb = 0; nb < 4; ++nb) {
        const half8 bv = *(const half8*)(ct1 + (nb * 16 + m16) * 64 +
                                         c * 32 + kb * 8);
#pragma unroll
        for (int mb = 0; mb < 5; ++mb)
          acc1[mb][nb] = __builtin_amdgcn_mfma_f32_16x16x32_f16(
              af1[mb], bv, acc1[mb][nb], 0, 0, 0);
      }
    }
    // write h1 rows into wave-private slab (proven C-layout transform)
#pragma unroll
    for (int mb = 0; mb < 5; ++mb)
#pragma unroll
      for (int nb = 0; nb < 4; ++nb) {
        const float bsv = ldf(bias1, nb * 16 + m16, f32);
#pragma unroll
        for (int r = 0; r < 4; ++r)
          myslab[(mb * 16 + kb * 4 + r) * PSTH + nb * 16 + m16] =
              f2h(acc1[mb][nb][r] + bsv);
      }
    // same-wave LDS RAW below (compiler orders); no barrier needed
  }

  f32x4 acc[MB][NB];
#pragma unroll
  for (int mb = 0; mb < MB; ++mb)
#pragma unroll
    for (int nb = 0; nb < NB; ++nb) {
      acc[mb][nb][0] = 0.f; acc[mb][nb][1] = 0.f;
      acc[mb][nb][2] = 0.f; acc[mb][nb][3] = 0.f;
    }

  // ---- A-fragment builder for chunk c (reads slab only) ----
  auto build_af = [&](int c, half8* af) {
    const int pg0 = c * 16 + kb * 4;
    if (pg0 < S1P) {
      // section 1: one angle, g=1..4 -> Chebyshev recurrence
      const int aa = pg0 >> 2;
      const int i = aa & (W - 1), w = aa >> LGW;
      const int hidx = S * w + i;
      const float hm = hamS[i];
#pragma unroll
      for (int mb = 0; mb < MB; ++mb) {
        const u16* rp = myslab + (mb * 16 + m16) * PSTH;
        const float th = h2f(rp[hidx]) * hm;
        const float c1 = __cosf(th), s1 = __sinf(th);
        const float tc = 2.0f * c1;
        const float c2 = tc * c1 - 1.0f, s2 = tc * s1;
        const float c3 = tc * c2 - c1,   s3 = tc * s2 - s1;
        const float c4 = tc * c3 - c2,   s4 = tc * s3 - s2;
        af[mb][0] = (_Float16)c1; af[mb][1] = (_Float16)s1;
        af[mb][2] = (_Float16)c2; af[mb][3] = (_Float16)s2;
        af[mb][4] = (_Float16)c3; af[mb][5] = (_Float16)s3;
        af[mb][6] = (_Float16)c4; af[mb][7] = (_Float16)s4;
      }
    } else {
      // section 2: g=5 tail, 4 distinct angles, direct cos/sin
      const int q0 = pg0 - S1P;
      float wm[4]; int hx[4];
#pragma unroll
      for (int u = 0; u < 4; ++u) {
        const int aa = q0 + u;
        const int i = aa & (W - 1), w = aa >> LGW;
        hx[u] = S * w + i;
        wm[u] = hamS[i] * 5.0f;
      }
#pragma unroll
      for (int mb = 0; mb < MB; ++mb) {
        const u16* rp = myslab + (mb * 16 + m16) * PSTH;
#pragma unroll
        for (int u = 0; u < 4; ++u) {
          const float ang = h2f(rp[hx[u]]) * wm[u];
          af[mb][2 * u]     = (_Float16)__cosf(ang);
          af[mb][2 * u + 1] = (_Float16)__sinf(ang);
        }
      }
    }
  };

  // ---- one pipelined chunk: uses afc (built last iter), builds afn ----
  auto step = [&](int c, half8* afc, half8* afn) {
    const bool havenext = (c + 1 < NCH);
    // issue next chunk's B global load (overlaps everything below)
    uint4 bnext[NPC];
    if (havenext) {
#pragma unroll
      for (int p_ = 0; p_ < NPC; ++p_)
        bnext[p_] = *(const uint4*)(srcB[p_] + (c + 1) * 32);
    }
    // build NEXT chunk's A fragments; MFMA below consumes afc from LAST
    // iter -> trans chain off the MFMA critical path
    if (havenext) build_af(c + 1, afn);
    // MFMA: bv loaded per-nb (keep live set small -- R24 spill lesson)
    const u16* bb = Bbuf + (c & 1) * BBS + kb * BCS;
#pragma unroll
    for (int nb = 0; nb < NB; ++nb) {
      const half8 bv = *(const half8*)(bb + (nb * 16 + m16) * 8);
#pragma unroll
      for (int mb = 0; mb < MB; ++mb)
        acc[mb][nb] = __builtin_amdgcn_mfma_f32_16x16x32_f16(
            afc[mb], bv, acc[mb][nb], 0, 0, 0);
    }
    // commit next chunk's B to LDS, barrier
    if (havenext) {
#pragma unroll
      for (int p_ = 0; p_ < NPC; ++p_)
        *(uint4*)(Bbuf + ((c + 1) & 1) * BBS + sdst[p_]) = bnext[p_];
      __syncthreads();
    }
  };

  half8 afA[MB], afB[MB];
  build_af(0, afA);
  constexpr int NCH2 = (NCH / 2) * 2;  // even part: L2 34, L3 70
  for (int c = 0; c < NCH2; c += 2) {
    step(c, afA, afB);
    step(c + 1, afB, afA);
  }
  if constexpr ((NCH & 1) != 0) {
    // odd tail (L2: c=34). step(NCH2-1, afB, afA) built afA=af(NCH-1);
    // buf[(NCH-1)&1] was committed+barriered there. Consume it.
    step(NCH - 1, afA, afB);
  }

  // ---- fused epilogues (C layout: row=kb*4+r, col=m16 within 16x16) ----
  if constexpr (L == 2) {
    // C-tile (80x128) -> dead slab (stride PSTH) in two 64-col passes,
    // maxpool over 20 rows each pass, write x1 fp16
    u16* st = myslab;
    const int pbase = tile * 16 + wv * 4;       // 4 points per wave
#pragma unroll
    for (int h = 0; h < 2; ++h) {
#pragma unroll
      for (int mb = 0; mb < MB; ++mb)
#pragma unroll
        for (int nb4 = 0; nb4 < 4; ++nb4) {
          const int nb = h * 4 + nb4;
          const float bsv = ldf(bias, nb * 16 + m16, f32);
#pragma unroll
          for (int r = 0; r < 4; ++r)
            st[(mb * 16 + kb * 4 + r) * PSTH + nb4 * 16 + m16] =
                f2h(acc[mb][nb][r] + bsv);
        }
#pragma unroll
      for (int j = 0; j < 4; ++j) {
        float m = -3.0e38f;
#pragma unroll
        for (int k = 0; k < 20; ++k)
          m = fmaxf(m, h2f(st[(j * 20 + k) * PSTH + lane]));
        ((u16*)out_)[(size_t)(pbase + j) * 128 + h * 64 + lane] = f2h(m);
      }
    }
  } else {
    // in-register max/sum over 32 rows + kb butterfly -> pmax/psum partials
    const int chunk = rowbase >> 5;
#pragma unroll
    for (int nb = 0; nb < NB; ++nb) {
      const int col = ncol0 + nb * 16 + m16;
      const float bsv = ldf(bias, col, f32);
      float m = -3.0e38f, s = 0.f;
#pragma unroll
      for (int mb = 0; mb < MB; ++mb)
#pragma unroll
        for (int r = 0; r < 4; ++r) {
          const float v = acc[mb][nb][r] + bsv;
          m = fmaxf(m, v); s += v;
        }
#pragma unroll
      for (int off = 16; off <= 32; off <<= 1) {
        m = fmaxf(m, __shfl_xor(m, off, 64));
        s += __shfl_xor(s, off, 64);
      }
      if (kb == 0) {
        pmax[(size_t)chunk * 1024 + col] = m;
        psum[(size_t)chunk * 1024 + col] = s;
      }
    }
  }
}

// ---------------- layer 4 partials (seg reduce fused in) --------------------
// R35: reads RAW c4 (no transpose). c4 natural layout [part][o][w][i][g]:
// per (part,o,w) the (i,g) run is 1280 contiguous floats. F is built as
// [part][i][g] (F[part*1280 + t*5 + g-1]); dot walks part0 then part1,
// both float4-aligned (1280 % 4 == 0, slice starts s*432 % 4 == 0).
// grid (15,8,2): z splits the 6 dot slices into 2x3 (240 blocks).
__global__ __launch_bounds__(256) void l4_kernel(const float* __restrict__ pmax,
                                                 const float* __restrict__ psum,
                                                 const void* __restrict__ c4,
                                                 const void* __restrict__ pos,
                                                 float* __restrict__ part) {
  __shared__ float F[2560];
  const int t = threadIdx.x;
  const bool f32 = wave_detect(pos);
  const int w = blockIdx.x, b = blockIdx.y, z = blockIdx.z;
  // fused segment combine (same reduce order as former seg2)
  const int ch = w * 128 + t;
  float xv;
  if (ch < 1024) {
    float m = -3.0e38f;
    for (int rc = 0; rc < 32; ++rc)
      m = fmaxf(m, pmax[(size_t)(b * 32 + rc) * 1024 + ch]);
    xv = m;
  } else {
    const int cc = ch - 1024;
    float s = 0.f;
    for (int rc = 0; rc < 32; ++rc)
      s += psum[(size_t)(b * 32 + rc) * 1024 + cc];
    xv = s * (1.0f / 1024.0f);
  }
  const float hm = 0.54f - 0.46f * cospif(2.0f * (float)t / 255.0f);
  const float aa = xv * hm;
  const float c1 = __cosf(aa), s1 = __sinf(aa);
  const float tc = 2.0f * c1;
  const float c2 = tc * c1 - 1.0f, s2 = tc * s1;
  const float c3 = tc * c2 - c1,   s3 = tc * s2 - s1;
  const float c4v = tc * c3 - c2,  s4 = tc * s3 - s2;
  const float a5 = aa * 5.0f;
  // F layout [part][i][g]: cos part at [t*5+g-1], sin part at [1280+t*5+g-1]
  F[t * 5]            = c1; F[t * 5 + 1]        = c2;
  F[t * 5 + 2]        = c3; F[t * 5 + 3]        = c4v;
  F[t * 5 + 4]        = __cosf(a5);
  F[1280 + t * 5]     = s1; F[1280 + t * 5 + 1] = s2;
  F[1280 + t * 5 + 2] = s3; F[1280 + t * 5 + 3] = s4;
  F[1280 + t * 5 + 4] = __sinf(a5);
  __syncthreads();
  if (t < 120) {
    const int o = t % 40, sl = t / 40;          // sl in [0,3)
    const int s = z * 3 + sl;                   // s in [0,6)
    const int f0 = s * 432;
    const int f1 = (f0 + 432 < 2560) ? (f0 + 432) : 2560;
    // c4 element offsets (in elements): part0 at o*19200 + w*1280,
    // part1 adds 40*19200 = 768000.
    const size_t base0 = (size_t)o * 19200 + (size_t)w * 1280;
    const size_t base1 = base0 + 768000;
    float acc = 0.f;
    for (int f = f0; f < f1; f += 4) {   // 1280 boundary is float4-aligned
      const size_t eoff = (f < 1280) ? (base0 + f) : (base1 + (f - 1280));
      float4 cv;
      if (f32) {
        cv = *(const float4*)((const float*)c4 + eoff);
      } else {
        const ushort4 uv = *(const ushort4*)((const u16*)c4 + eoff);
        cv = make_float4(bf2f(uv.x), bf2f(uv.y), bf2f(uv.z), bf2f(uv.w));
      }
      const float4 fa = *(const float4*)&F[f];
      acc += fa.x * cv.x + fa.y * cv.y + fa.z * cv.z + fa.w * cv.w;
    }
    part[((b * 15 + w) * 6 + s) * 40 + o] = acc;
  }
}

__global__ void outred_kernel(const float* __restrict__ part,
                              const void* __restrict__ b4,
                              const void* __restrict__ pos,
                              void* __restrict__ outp) {
  int t = threadIdx.x;
  const bool f32 = wave_detect(pos);
  if (t >= 320) return;
  int b = t / 40, o = t % 40;
  float s = ldf(b4, o, f32);
  for (int w = 0; w < 15; ++w)
#pragma unroll
    for (int sl = 0; sl < 6; ++sl)
      s += part[((b * 15 + w) * 6 + sl) * 40 + o];
  if (f32) ((float*)outp)[t] = s;
  else     ((u16*)outp)[t] = f2bfr(s);
}

// ---------------------------------------------------------------------------
extern "C" void kernel_launch(void* const* d_in, const int* in_sizes, int n_in,
                              void* d_out, int out_size, void* d_ws,
                              size_t ws_size, hipStream_t stream) {
  (void)in_sizes; (void)n_in; (void)out_size; (void)ws_size;
  const void* pos = d_in[0];
  // d_in[1] = batch (int32) -- clouds are sorted equal-size, used implicitly
  const void* c1 = d_in[2];
  const void* b1 = d_in[3];
  const void* c2 = d_in[4];
  const void* b2 = d_in[5];
  const void* c3 = d_in[6];
  const void* b3 = d_in[7];
  const void* c4 = d_in[8];
  const void* b4 = d_in[9];

  char* ws = (char*)d_ws;
  int* nbr   = (int*)(ws + NBR_OFF);
  float* l4p = (float*)(ws + L4P_OFF);
  u16* c1t   = (u16*)(ws + C1T_OFF);
  u16* c2t   = (u16*)(ws + C2T_OFF);
  u16* c3t   = (u16*)(ws + C3T_OFF);
  float* pmax = (float*)(ws + PMAX_OFF);
  float* psum = (float*)(ws + PSUM_OFF);
  u16* x1    = (u16*)(ws + X1_OFF);

  // merged prep: knn (blocks [0,2048)) + coeff transpose ([2048,11584));
  // c4 transpose deleted (l4 reads raw c4 directly)
  prep_kernel<<<11584, 256, 0, stream>>>(pos, nbr, c1, c1t, c2, c2t,
                                         c3, c3t);

  // L1+L2 fused: 512 blocks x 320 rows; each wave computes its 80 h1 rows
  // in-slab (embedded L1) then runs the NT=128 L2 + maxpool
  kan_kernel<2><<<dim3(512), 256, 0, stream>>>(nullptr, nbr, pos, c2t,
                                               b2, x1, nullptr, nullptr,
                                               c1t, b1);
  // L3 fused segment partials: 1024 linear blocks, XCD-swizzled inside
  kan_kernel<3><<<1024, 256, 0, stream>>>(x1, nullptr, pos, c3t,
                                          b3, nullptr, pmax, psum,
                                          nullptr, nullptr);

  l4_kernel<<<dim3(15, 8, 2), 256, 0, stream>>>(pmax, psum, c4, pos, l4p);
  outred_kernel<<<1, 320, 0, stream>>>(l4p, b4, pos, d_out);
}